// Round 11
// baseline (911.790 us; speedup 1.0000x reference)
//
#include <hip/hip_runtime.h>
#include <hip/hip_fp8.h>
#include <stdint.h>

#define D     512
#define BM    128
#define BN    128
#define BKC   128          // k-bytes per fp8 chunk; 4 chunks per kt; ring of 4
#define CAND  64
#define MARGIN 7e-4f       // unscaled; screen works at 8192x scale
#define MARGINS (8192.0f * MARGIN)
#define KDIM  8192

typedef __attribute__((ext_vector_type(4))) float f32x4;
typedef unsigned long long u64;

__device__ __forceinline__ unsigned char f2fp8(float f) {
  __hip_fp8_e4m3 q(f);                       // OCP e4m3fn, SATFINITE
  return (unsigned char)q.__x;
}

__device__ __forceinline__ unsigned fkey(float f) {
  unsigned u = __float_as_uint(f);
  return (u >> 31) ? ~u : (u | 0x80000000u);
}
__device__ __forceinline__ float unfkey(unsigned k) {
  unsigned u = (k >> 31) ? (k & 0x7FFFFFFFu) : ~k;
  return __uint_as_float(u);
}

// ---------------- prep: codebook -> fp8(w*8192), b32[k] = fp32(sum_fp64 of fp32 squares)
__global__ __launch_bounds__(256) void vq_prep(const float* __restrict__ cb,
                                               unsigned char* __restrict__ w8,
                                               float* __restrict__ b32, int K) {
  int wid  = blockIdx.x * 4 + (threadIdx.x >> 6);
  int lane = threadIdx.x & 63;
  if (wid >= K) return;
  const float* row = cb + (size_t)wid * D + lane * 8;
  float4 a = *(const float4*)row;
  float4 b = *(const float4*)(row + 4);
  float v[8] = {a.x, a.y, a.z, a.w, b.x, b.y, b.z, b.w};
  double s = 0.0;
  u64 p = 0ull;
#pragma unroll
  for (int j = 0; j < 8; ++j) {
    float sq = v[j] * v[j]; s += (double)sq;
    p |= (u64)f2fp8(v[j] * 8192.0f) << (8 * j);
  }
  *(u64*)(w8 + (size_t)wid * D + lane * 8) = p;
#pragma unroll
  for (int m = 1; m < 64; m <<= 1) s += __shfl_xor(s, m);
  if (lane == 0) b32[wid] = (float)s;
}

// DMA one 16KB fp8 chunk (kt2, c2) into wb[c2]: linear LDS dest, inverse-swizzled
// global source. Swizzle: 16B-slot j within a 128B row -> j ^ (row & 7).
__device__ __forceinline__ void stage2(const unsigned char* __restrict__ w8,
                                       unsigned char (*wb)[BN * BKC], int kt2, int c2,
                                       int w, int lane) {
#pragma unroll
  for (int i = 0; i < 2; ++i) {
    const int sb  = (w * 2 + i) * 64;     // 16B-slot base for this issue
    const int s   = sb + lane;            // 0..1023
    const int row = s >> 3;               // 8 slots per 128B row
    const int j   = s & 7;
    const int k16 = j ^ (row & 7);        // inverse swizzle on the source
    const unsigned char* src = w8 + (size_t)(kt2 * BN + row) * D + c2 * BKC + k16 * 16;
    unsigned char* dst = &wb[c2][sb * 16];  // wave-uniform base; HW adds lane*16B
    __builtin_amdgcn_global_load_lds(
        (const __attribute__((address_space(1))) unsigned int*)src,
        (__attribute__((address_space(3))) unsigned int*)dst, 16, 0, 0);
  }
}

// ---------------- main: A-in-regs fp8 MFMA screen + exact fp32-mimic rescore
// BM=128, 1 block/CU (LDS-limited). Wave grid 2(row-groups of 64) x 4(col-
// groups of 32): mi=4, ni=2 -> per-wave LDS B-reads halved (A in registers).
// waves_per_eu(2,2): LDS caps the CU at 1 block = 2 waves/EU; without the
// explicit MAX the backend's regalloc targets 4 waves/EU (cap 128 VGPR) and
// spills afr to scratch (r9/r10: VGPR=128, +0.44GB scratch writes).
__global__
__attribute__((amdgpu_flat_work_group_size(512, 512), amdgpu_waves_per_eu(2, 2)))
void vq_main(
    const float* __restrict__ x, const float* __restrict__ cb,
    const unsigned char* __restrict__ w8, const float* __restrict__ b32g,
    float* __restrict__ out_q, float* __restrict__ out_enc, float* __restrict__ out_idx,
    int N, int K) {
  __shared__ unsigned char wb[4][BN * BKC];   // 64 KiB: 4-chunk ring of fp8 B tiles
  __shared__ unsigned rowmin[BM];
  __shared__ unsigned rowcnt[BM];
  __shared__ u64 candb[BM][CAND];             // 64 KiB: (fkey(tv)<<32 | k)

  const int t    = threadIdx.x;
  const int lane = t & 63;
  const int w    = t >> 6;           // 0..7
  const int wr   = w & 1;            // 0..1  row group of 64
  const int wc   = w >> 1;           // 0..3  col group of 32
  const int l15  = lane & 15;
  const int l16  = lane >> 4;        // 0..3
  const int m_base = blockIdx.x * BM;
  const int nkt  = K / BN;
  float* const enc_blk = out_enc + (size_t)m_base * K;   // this block's 4MB slab

  if (t < BM) { rowmin[t] = 0xFFFFFFFFu; rowcnt[t] = 0u; }

  // issue first two chunks of kt=0 while we load/convert A into registers
  stage2(w8, wb, 0, 0, w, lane);
  stage2(w8, wb, 0, 1, w, lane);

  // ---- A fragments resident in registers as fp8: afr[mi][f] covers k=f*32..+32
  long afr[4][16];
#pragma unroll
  for (int mi = 0; mi < 4; ++mi) {
    const float* xr = x + (size_t)(m_base + 64 * wr + 16 * mi + l15) * D;
#pragma unroll
    for (int f = 0; f < 16; ++f) {
      const float* p = xr + f * 32 + l16 * 8;
      float4 a = *(const float4*)p;
      float4 b = *(const float4*)(p + 4);
      float v[8] = {a.x, a.y, a.z, a.w, b.x, b.y, b.z, b.w};
      u64 pk = 0ull;
#pragma unroll
      for (int j = 0; j < 8; ++j) pk |= (u64)f2fp8(v[j]) << (8 * j);
      afr[mi][f] = (long)pk;
    }
  }
  __syncthreads();   // drains prologue DMAs + publishes rowmin init

  for (int kt = 0; kt < nkt; ++kt) {
    float b32v[2];
#pragma unroll
    for (int ni = 0; ni < 2; ++ni)
      b32v[ni] = 8192.0f * b32g[kt * BN + 32 * wc + 16 * ni + l15];   // scaled for screen

    f32x4 acc[4][2];
#pragma unroll
    for (int mi = 0; mi < 4; ++mi)
#pragma unroll
      for (int ni = 0; ni < 2; ++ni) acc[mi][ni] = (f32x4){0.f, 0.f, 0.f, 0.f};

#pragma unroll
    for (int c = 0; c < 4; ++c) {
      // DMA for chunk g+2 then 2 enc-zero stores (all in the newest-in-flight group)
      const int kt2 = kt + ((c + 2) >> 2);
      if (kt2 < nkt) stage2(w8, wb, kt2, (c + 2) & 3, w, lane);
      {
        const f32x4 z4 = {0.f, 0.f, 0.f, 0.f};
        f32x4* ez = (f32x4*)(enc_blk + (size_t)kt * (BM * KDIM / 64));
        __builtin_nontemporal_store(z4, ez + (c * 2 + 0) * 512 + t);
        __builtin_nontemporal_store(z4, ez + (c * 2 + 1) * 512 + t);
      }

      // compute on chunk c (resident; vmcnt chain guarantees)
      const unsigned char* wp = &wb[c][0];
      __builtin_amdgcn_s_setprio(1);
#pragma unroll
      for (int ks = 0; ks < 4; ++ks) {
        long bfr[2];
#pragma unroll
        for (int ni = 0; ni < 2; ++ni) {
          const int row  = 32 * wc + 16 * ni + l15;
          const int slot = (ks * 2 + (l16 >> 1)) ^ (row & 7);
          bfr[ni] = *(const long*)(wp + row * BKC + slot * 16 + (l16 & 1) * 8);
        }
#pragma unroll
        for (int mi = 0; mi < 4; ++mi)
#pragma unroll
          for (int ni = 0; ni < 2; ++ni)
            acc[mi][ni] = __builtin_amdgcn_mfma_f32_16x16x32_fp8_fp8(
                afr[mi][c * 4 + ks], bfr[ni], acc[mi][ni], 0, 0, 0);
      }
      __builtin_amdgcn_s_setprio(0);
      // counted wait, 6 newest kept: waits only on chunk c+1's DMA (1 phase old)
      // and stores >=2 phases old. Chunk c+1 is resident at the barrier.
      if (kt2 < nkt) asm volatile("s_waitcnt vmcnt(6)" ::: "memory");
      else           asm volatile("s_waitcnt vmcnt(0)" ::: "memory");
      __builtin_amdgcn_sched_barrier(0);
      __builtin_amdgcn_s_barrier();
    }

    // ---- epilogue (8192x scale): lazy rowmin + margin collect w/ stored tv.
    // rowmin monotone; stale reads only loosen the threshold -> superset.
    float tv[4][2][4];
#pragma unroll
    for (int mi = 0; mi < 4; ++mi)
#pragma unroll
      for (int ni = 0; ni < 2; ++ni)
#pragma unroll
        for (int r = 0; r < 4; ++r)
          tv[mi][ni][r] = fmaf(-2.0f, acc[mi][ni][r], b32v[ni]);

    if (kt == 0) {   // prime rowmin so the margin test never sees +inf
#pragma unroll
      for (int mi = 0; mi < 4; ++mi)
#pragma unroll
        for (int r = 0; r < 4; ++r)
          atomicMin(&rowmin[64 * wr + 16 * mi + 4 * l16 + r],
                    fkey(fminf(tv[mi][0][r], tv[mi][1][r])));
      __syncthreads();
    }

#pragma unroll
    for (int mi = 0; mi < 4; ++mi) {
      const int rbase = 64 * wr + 16 * mi + 4 * l16;
      const uint4 ru = *(const uint4*)&rowmin[rbase];
      const unsigned rua[4] = {ru.x, ru.y, ru.z, ru.w};
#pragma unroll
      for (int r = 0; r < 4; ++r) {
        const float rm  = unfkey(rua[r]);
        const float thr = rm + MARGINS;
        const float mn  = fminf(tv[mi][0][r], tv[mi][1][r]);
        if (mn < rm) atomicMin(&rowmin[rbase + r], fkey(mn));
#pragma unroll
        for (int ni = 0; ni < 2; ++ni) {
          if (tv[mi][ni][r] <= thr) {
            unsigned p = atomicAdd(&rowcnt[rbase + r], 1u);
            if (p < CAND)
              candb[rbase + r][p] = ((u64)fkey(tv[mi][ni][r]) << 32)
                                  | (unsigned)(kt * BN + 32 * wc + 16 * ni + l15);
          }
        }
      }
    }
  }
  __syncthreads();   // protects candb/rowcnt; drains last nt zero-stores

  // ---- finalize: filter by FINAL rowmin, 4-wide exact fp32-mimic rescore.
  // Lane group g=l16 takes candidate i+g; 16 lanes x 32 elems per dot.
  for (int r = w; r < BM; r += 8) {
    const int n = m_base + r;
    const float* xr = x + (size_t)n * D + l15 * 32;
    float xv[32];
#pragma unroll
    for (int j4 = 0; j4 < 8; ++j4) {
      float4 v = *(const float4*)(xr + j4 * 4);
      xv[j4 * 4 + 0] = v.x; xv[j4 * 4 + 1] = v.y;
      xv[j4 * 4 + 2] = v.z; xv[j4 * 4 + 3] = v.w;
    }
    double s = 0.0;
#pragma unroll
    for (int j = 0; j < 32; ++j) { float sq = xv[j] * xv[j]; s += (double)sq; }
#pragma unroll
    for (int m = 1; m < 16; m <<= 1) s += __shfl_xor(s, m);
    const float Arow = (float)s;   // fp32(sum_fp64 x^2); uniform shift keeps argmin

    const unsigned cgot = rowcnt[r];
    const bool uselist = (cgot >= 1u && cgot <= (unsigned)CAND);
    const int nc = uselist ? (int)cgot : K;   // overflow => exact full scan (safety net)
    const float thrF = unfkey(rowmin[r]) + MARGINS;   // FINAL threshold
    u64 best = 0xFFFFFFFFFFFFFFFFull;

    for (int i = 0; i < nc; i += 4) {
      const int ci = i + l16;
      if (ci < nc) {
        int k; bool ok = true;
        if (uselist) {
          const u64 e = candb[r][ci];
          k = (int)(e & 0xFFFFFFFFu);
          ok = (unfkey((unsigned)(e >> 32)) <= thrF);  // drop immature-min extras
        } else k = ci;
        if (ok) {
          const float* wp = cb + (size_t)k * D + l15 * 32;
          double d = 0.0;
#pragma unroll
          for (int j4 = 0; j4 < 8; ++j4) {
            float4 v = *(const float4*)(wp + j4 * 4);
            d += (double)xv[j4 * 4 + 0] * v.x; d += (double)xv[j4 * 4 + 1] * v.y;
            d += (double)xv[j4 * 4 + 2] * v.z; d += (double)xv[j4 * 4 + 3] * v.w;
          }
#pragma unroll
          for (int m = 1; m < 16; m <<= 1) d += __shfl_xor(d, m);
          const float C32 = (float)d;                 // fp32(x . w_k)
          const float T1  = Arow + b32g[k];           // fp32(A + B) as reference
          const float sc  = T1 - 2.0f * C32;          // one final rounding; sc > 0
          const u64 pk = ((u64)__float_as_uint(sc) << 32) | (unsigned)k;
          best = best < pk ? best : pk;               // lowest-index tie-break
        }
      }
    }
    // combine across the 4 lane groups
    {
      u64 o = __shfl_xor(best, 16); best = best < o ? best : o;
      o     = __shfl_xor(best, 32); best = best < o ? best : o;
    }
    const int kstar = (int)(best & 0xFFFFFFFFu);

    if (lane == 0) {
      out_idx[n] = (float)kstar;
      out_enc[(size_t)n * K + kstar] = 1.0f;      // patch after zero-drain
    }
    const float* qs = cb + (size_t)kstar * D + lane * 8;
    float4 q0 = *(const float4*)qs;
    float4 q1 = *(const float4*)(qs + 4);
    f32x4* qd = (f32x4*)(out_q + (size_t)n * D + lane * 8);
    f32x4 q0v = {q0.x, q0.y, q0.z, q0.w};
    f32x4 q1v = {q1.x, q1.y, q1.z, q1.w};
    __builtin_nontemporal_store(q0v, qd);
    __builtin_nontemporal_store(q1v, qd + 1);
  }
}

extern "C" void kernel_launch(void* const* d_in, const int* in_sizes, int n_in,
                              void* d_out, int out_size, void* d_ws, size_t ws_size,
                              hipStream_t stream) {
  const float* x  = (const float*)d_in[0];
  const float* cb = (const float*)d_in[1];
  const int N = in_sizes[0] / D;
  const int K = in_sizes[1] / D;

  unsigned char* w8 = (unsigned char*)d_ws;                       // K*512 fp8 (4 MiB)
  float* b32 = (float*)((char*)d_ws + (size_t)K * D);

  float* out     = (float*)d_out;
  float* out_q   = out;
  float* out_enc = out + (size_t)N * D;
  float* out_idx = out + (size_t)N * D + (size_t)N * K;

  // No memset: vq_main writes the full one-hot rows (zeros + patch) itself.
  vq_prep<<<(K + 3) / 4, 256, 0, stream>>>(cb, w8, b32, K);
  vq_main<<<N / BM, 512, 0, stream>>>(x, cb, w8, b32, out_q, out_enc, out_idx, N, K);
}

// Round 12
// 457.086 us; speedup vs baseline: 1.9948x; 1.9948x over previous
//
#include <hip/hip_runtime.h>
#include <stdint.h>

#define D     512
#define BM    128
#define BN    128
#define BK    128          // k-elems per chunk; 4 chunks per kt
#define CAND  48
#define MARGIN 5e-4f
#define KDIM  8192

typedef __attribute__((ext_vector_type(4))) float f32x4;
typedef __attribute__((ext_vector_type(8))) short s16x8;   // 8 x bf16 bits (4 VGPR)
typedef unsigned long long u64;

__device__ __forceinline__ short f2bf(float f) {
  unsigned u = __float_as_uint(f);
  u = (u + 0x7FFFu + ((u >> 16) & 1u)) >> 16;   // RNE fp32 -> bf16
  return (short)u;
}

__device__ __forceinline__ s16x8 pack_bf8(float4 a, float4 b) {
  s16x8 v;
  v[0] = f2bf(a.x); v[1] = f2bf(a.y); v[2] = f2bf(a.z); v[3] = f2bf(a.w);
  v[4] = f2bf(b.x); v[5] = f2bf(b.y); v[6] = f2bf(b.z); v[7] = f2bf(b.w);
  return v;
}

__device__ __forceinline__ unsigned fkey(float f) {
  unsigned u = __float_as_uint(f);
  return (u >> 31) ? ~u : (u | 0x80000000u);
}
__device__ __forceinline__ float unfkey(unsigned k) {
  unsigned u = (k >> 31) ? (k & 0x7FFFFFFFu) : ~k;
  return __uint_as_float(u);
}

// ---------------- prep: codebook -> bf16, B32[k] = fp32(sum_fp64 of fp32 squares)
__global__ __launch_bounds__(256) void vq_prep(const float* __restrict__ cb,
                                               unsigned short* __restrict__ wh,
                                               float* __restrict__ b32, int K) {
  int wid  = blockIdx.x * 4 + (threadIdx.x >> 6);
  int lane = threadIdx.x & 63;
  if (wid >= K) return;
  const float* row = cb + (size_t)wid * D + lane * 8;
  float4 a = *(const float4*)row;
  float4 b = *(const float4*)(row + 4);
  float v[8] = {a.x, a.y, a.z, a.w, b.x, b.y, b.z, b.w};
  double s = 0.0;
#pragma unroll
  for (int j = 0; j < 8; ++j) { float sq = v[j] * v[j]; s += (double)sq; }
  s16x8 p = pack_bf8(a, b);
  *(s16x8*)((short*)wh + (size_t)wid * D + lane * 8) = p;
#pragma unroll
  for (int m = 1; m < 64; m <<= 1) s += __shfl_xor(s, m);
  if (lane == 0) b32[wid] = (float)s;
}

// DMA one 32KB chunk (kt2, c2) into wb[c2]: linear LDS dest, inverse-swizzled
// global source (swizzle: 16B-slot ^= row&15 within each 256B row).
__device__ __forceinline__ void stage4(const unsigned short* __restrict__ wh,
                                       short (*wb)[BN * BK], int kt2, int c2,
                                       int w, int lane) {
#pragma unroll
  for (int i = 0; i < 4; ++i) {
    const int sb  = (w * 4 + i) * 64;     // 16B-slot base for this issue
    const int s   = sb + lane;
    const int row = s >> 4;               // 16 slots per 256B row
    const int sir = s & 15;
    const int ksl = sir ^ (row & 15);     // inverse swizzle on the source
    const unsigned short* src = wh + (size_t)(kt2 * BN + row) * D + c2 * BK + ksl * 8;
    short* dst = &wb[c2][sb * 8];         // wave-uniform base; HW adds lane*16B
    __builtin_amdgcn_global_load_lds(
        (const __attribute__((address_space(1))) unsigned int*)src,
        (__attribute__((address_space(3))) unsigned int*)dst, 16, 0, 0);
  }
}

// ---------------- main: A-in-regs bf16 MFMA screen + exact fp32-mimic rescore
// BM=128, 1 block/CU, wave grid 4(row-groups of 32) x 2(col-groups of 64).
// == r5 (best measured, 463us) with ONLY the finalize upgraded to 4-wide.
__global__ __launch_bounds__(512, 2) void vq_main(
    const float* __restrict__ x, const float* __restrict__ cb,
    const unsigned short* __restrict__ wh, const float* __restrict__ b32g,
    float* __restrict__ out_q, float* __restrict__ out_enc, float* __restrict__ out_idx,
    int N, int K) {
  __shared__ short wb[4][BN * BK];        // 128 KiB: 4-chunk ring of B tiles
  __shared__ unsigned rowmin[BM];
  __shared__ unsigned rowcnt[BM];
  __shared__ unsigned candb[BM][CAND];    // 24 KiB

  const int t    = threadIdx.x;
  const int lane = t & 63;
  const int w    = t >> 6;           // 0..7
  const int wr   = w >> 1;           // 0..3  row group of 32
  const int wc   = w & 1;            // 0..1  col group of 64
  const int l15  = lane & 15;
  const int l16  = lane >> 4;        // 0..3
  const int m_base = blockIdx.x * BM;
  const int nkt  = K / BN;
  float* const enc_blk = out_enc + (size_t)m_base * K;   // this block's 4MB slab

  if (t < BM) { rowmin[t] = 0xFFFFFFFFu; rowcnt[t] = 0u; }

  // issue first two chunks of kt=0 while we load A into registers
  stage4(wh, wb, 0, 0, w, lane);
  stage4(wh, wb, 0, 1, w, lane);

  // ---- A fragments resident in registers: afr[mi][f], f = k-step (32 elems)
  s16x8 afr[2][16];
#pragma unroll
  for (int mi = 0; mi < 2; ++mi) {
    const float* xr = x + (size_t)(m_base + 32 * wr + 16 * mi + l15) * D;
#pragma unroll
    for (int f = 0; f < 16; ++f) {
      const float* p = xr + (f * 4 + l16) * 8;
      float4 a = *(const float4*)p;
      float4 b = *(const float4*)(p + 4);
      afr[mi][f] = pack_bf8(a, b);
    }
  }
  __syncthreads();   // drains prologue DMAs + publishes rowmin init

  for (int kt = 0; kt < nkt; ++kt) {
    float b32v[4];
#pragma unroll
    for (int ni = 0; ni < 4; ++ni)
      b32v[ni] = b32g[kt * BN + 64 * wc + 16 * ni + l15];

    f32x4 acc[2][4];
#pragma unroll
    for (int mi = 0; mi < 2; ++mi)
#pragma unroll
      for (int ni = 0; ni < 4; ++ni) acc[mi][ni] = (f32x4){0.f, 0.f, 0.f, 0.f};

#pragma unroll
    for (int c = 0; c < 4; ++c) {
      // 2 encodings-zero stores FIRST (older than the prefetch in vmcnt queue;
      // drained by this phase's vmcnt(4) after a full MFMA phase of slack)
      {
        const f32x4 z4 = {0.f, 0.f, 0.f, 0.f};
        f32x4* ez = (f32x4*)(enc_blk + (size_t)kt * (BM * KDIM / 64));
        __builtin_nontemporal_store(z4, ez + (c * 2 + 0) * 512 + t);
        __builtin_nontemporal_store(z4, ez + (c * 2 + 1) * 512 + t);
      }
      // issue DMA for chunk g+2 (buffer (c+2)&3; its readers finished 2 barriers ago)
      const int kt2 = kt + ((c + 2) >> 2);
      if (kt2 < nkt) stage4(wh, wb, kt2, (c + 2) & 3, w, lane);

      // compute on chunk c (resident; vmcnt chain guarantees)
      const short* wp = &wb[c][0];
      __builtin_amdgcn_s_setprio(1);
#pragma unroll
      for (int ks = 0; ks < 4; ++ks) {
        s16x8 bfr[4];
#pragma unroll
        for (int ni = 0; ni < 4; ++ni) {
          const int row = 64 * wc + 16 * ni + l15;
          const int sl  = (ks * 4 + l16) ^ (row & 15);
          bfr[ni] = *(const s16x8*)(wp + row * BK + sl * 8);
        }
#pragma unroll
        for (int mi = 0; mi < 2; ++mi)
#pragma unroll
          for (int ni = 0; ni < 4; ++ni)
            acc[mi][ni] = __builtin_amdgcn_mfma_f32_16x16x32_bf16(
                afr[mi][c * 4 + ks], bfr[ni], acc[mi][ni], 0, 0, 0);
      }
      __builtin_amdgcn_s_setprio(0);
      // counted wait: keep newest 4 (chunk g+2 DMA) in flight; drains chunk g+1
      // DMA and this phase's 2 stores (both older than the g+2 issues).
      if (kt2 < nkt) asm volatile("s_waitcnt vmcnt(4)" ::: "memory");
      else           asm volatile("s_waitcnt vmcnt(0)" ::: "memory");
      __builtin_amdgcn_sched_barrier(0);
      __builtin_amdgcn_s_barrier();
    }

    // ---- epilogue: tv = B - 2*dot (bf16 approx); lazy rowmin + margin collect.
    // rowmin is monotone; stale reads only loosen the threshold -> superset.
    float tv[2][4][4];
#pragma unroll
    for (int mi = 0; mi < 2; ++mi)
#pragma unroll
      for (int ni = 0; ni < 4; ++ni)
#pragma unroll
        for (int r = 0; r < 4; ++r)
          tv[mi][ni][r] = fmaf(-2.0f, acc[mi][ni][r], b32v[ni]);

    if (kt == 0) {   // prime rowmin so the margin test never sees +inf
#pragma unroll
      for (int mi = 0; mi < 2; ++mi)
#pragma unroll
        for (int r = 0; r < 4; ++r) {
          float m = fminf(fminf(tv[mi][0][r], tv[mi][1][r]),
                          fminf(tv[mi][2][r], tv[mi][3][r]));
          atomicMin(&rowmin[32 * wr + 16 * mi + 4 * l16 + r], fkey(m));
        }
      __syncthreads();
    }

#pragma unroll
    for (int mi = 0; mi < 2; ++mi) {
      const int rbase = 32 * wr + 16 * mi + 4 * l16;
      const uint4 ru = *(const uint4*)&rowmin[rbase];
      const unsigned rua[4] = {ru.x, ru.y, ru.z, ru.w};
#pragma unroll
      for (int r = 0; r < 4; ++r) {
        const float rm  = unfkey(rua[r]);
        const float thr = rm + MARGIN;
        const float mn  = fminf(fminf(tv[mi][0][r], tv[mi][1][r]),
                                fminf(tv[mi][2][r], tv[mi][3][r]));
        if (mn < rm) atomicMin(&rowmin[rbase + r], fkey(mn));
#pragma unroll
        for (int ni = 0; ni < 4; ++ni) {
          if (tv[mi][ni][r] <= thr) {
            unsigned p = atomicAdd(&rowcnt[rbase + r], 1u);
            if (p < CAND) candb[rbase + r][p] = (unsigned)(kt * BN + 64 * wc + 16 * ni + l15);
          }
        }
      }
    }
  }
  __syncthreads();   // protects candb/rowcnt; drains last nt zero-stores

  // ---- finalize: 4-wide exact fp32-mimic rescore (lane group g=l16 takes
  // candidate i+g; 16 lanes x 32 elems per fp64 dot; packed-u64 argmin merge).
  for (int r = w; r < BM; r += 8) {
    const int n = m_base + r;
    const float* xr = x + (size_t)n * D + l15 * 32;
    float xv[32];
#pragma unroll
    for (int j4 = 0; j4 < 8; ++j4) {
      float4 v = *(const float4*)(xr + j4 * 4);
      xv[j4 * 4 + 0] = v.x; xv[j4 * 4 + 1] = v.y;
      xv[j4 * 4 + 2] = v.z; xv[j4 * 4 + 3] = v.w;
    }
    double s = 0.0;
#pragma unroll
    for (int j = 0; j < 32; ++j) { float sq = xv[j] * xv[j]; s += (double)sq; }
#pragma unroll
    for (int m = 1; m < 16; m <<= 1) s += __shfl_xor(s, m);
    const float Arow = (float)s;   // fp32(sum_fp64 x^2); uniform shift keeps argmin

    const unsigned cgot = rowcnt[r];
    const bool uselist = (cgot >= 1u && cgot <= (unsigned)CAND);
    const int nc = uselist ? (int)cgot : K;   // overflow => exact full scan (safety net)
    u64 best = 0xFFFFFFFFFFFFFFFFull;

    for (int i = 0; i < nc; i += 4) {
      const int ci = i + l16;
      if (ci < nc) {
        const int k = uselist ? (int)candb[r][ci] : ci;
        const float* wp = cb + (size_t)k * D + l15 * 32;
        double d = 0.0;
#pragma unroll
        for (int j4 = 0; j4 < 8; ++j4) {
          float4 v = *(const float4*)(wp + j4 * 4);
          d += (double)xv[j4 * 4 + 0] * v.x; d += (double)xv[j4 * 4 + 1] * v.y;
          d += (double)xv[j4 * 4 + 2] * v.z; d += (double)xv[j4 * 4 + 3] * v.w;
        }
#pragma unroll
        for (int m = 1; m < 16; m <<= 1) d += __shfl_xor(d, m);
        const float C32 = (float)d;                 // fp32(x . w_k)
        const float T1  = Arow + b32g[k];           // fp32(A + B) as reference
        const float sc  = T1 - 2.0f * C32;          // one final rounding
        const u64 pk = ((u64)__float_as_uint(sc) << 32) | (unsigned)k;
        best = best < pk ? best : pk;               // lowest-index tie-break
      }
    }
    // combine across the 4 lane groups
    {
      u64 o = __shfl_xor(best, 16); best = best < o ? best : o;
      o     = __shfl_xor(best, 32); best = best < o ? best : o;
    }
    const int kstar = (int)(best & 0xFFFFFFFFu);

    if (lane == 0) {
      out_idx[n] = (float)kstar;
      out_enc[(size_t)n * K + kstar] = 1.0f;      // patch after zero-drain
    }
    const float* qs = cb + (size_t)kstar * D + lane * 8;
    float4 q0 = *(const float4*)qs;
    float4 q1 = *(const float4*)(qs + 4);
    f32x4* qd = (f32x4*)(out_q + (size_t)n * D + lane * 8);
    f32x4 q0v = {q0.x, q0.y, q0.z, q0.w};
    f32x4 q1v = {q1.x, q1.y, q1.z, q1.w};
    __builtin_nontemporal_store(q0v, qd);
    __builtin_nontemporal_store(q1v, qd + 1);
  }
}

extern "C" void kernel_launch(void* const* d_in, const int* in_sizes, int n_in,
                              void* d_out, int out_size, void* d_ws, size_t ws_size,
                              hipStream_t stream) {
  const float* x  = (const float*)d_in[0];
  const float* cb = (const float*)d_in[1];
  const int N = in_sizes[0] / D;
  const int K = in_sizes[1] / D;

  unsigned short* wh = (unsigned short*)d_ws;                       // K*512 bf16 (8 MiB)
  float* b32 = (float*)((char*)d_ws + (size_t)K * D * sizeof(unsigned short));

  float* out     = (float*)d_out;
  float* out_q   = out;
  float* out_enc = out + (size_t)N * D;
  float* out_idx = out + (size_t)N * D + (size_t)N * K;

  // No memset: vq_main writes the full one-hot rows (zeros + patch) itself.
  vq_prep<<<(K + 3) / 4, 256, 0, stream>>>(cb, wh, b32, K);
  vq_main<<<N / BM, 512, 0, stream>>>(x, cb, wh, b32, out_q, out_enc, out_idx, N, K);
}